// Round 1
// baseline (1437.013 us; speedup 1.0000x reference)
//
#include <hip/hip_runtime.h>
#include <stdint.h>

#define SEQ 2048
#define DM  2048
#define NH  16
#define HD  128
#define DFF 8192

typedef float  f32x4  __attribute__((ext_vector_type(4)));
typedef __bf16 bf16x8 __attribute__((ext_vector_type(8)));
typedef unsigned short u16x8 __attribute__((ext_vector_type(8)));

__device__ __forceinline__ unsigned short f2bf(float f) {
  union { float f; uint32_t u; } c; c.f = f;
  uint32_t u = c.u;
  uint32_t r = (u + 0x7fffu + ((u >> 16) & 1u)) >> 16;
  return (unsigned short)r;
}
__device__ __forceinline__ float bf2f(unsigned short h) {
  union { uint32_t u; float f; } c; c.u = ((uint32_t)h) << 16;
  return c.f;
}

__device__ __forceinline__ void gload_lds16(const void* g, void* s) {
  __builtin_amdgcn_global_load_lds((const __attribute__((address_space(1))) void*)g,
                                   (__attribute__((address_space(3))) void*)s, 16, 0, 0);
}

// ---------------- f32 -> bf16 cast ----------------
__global__ void cast_f32_bf16(const float4* __restrict__ in, unsigned short* __restrict__ out, int n4) {
  int i = blockIdx.x * 256 + threadIdx.x;
  if (i >= n4) return;
  float4 v = in[i];
  ushort4 o;
  o.x = f2bf(v.x); o.y = f2bf(v.y); o.z = f2bf(v.z); o.w = f2bf(v.w);
  *(ushort4*)&out[(size_t)i * 4] = o;
}

// ---------------- RMSNorm: f32 row -> bf16 row ----------------
__launch_bounds__(256)
__global__ void rmsnorm_k(const float* __restrict__ x, const float* __restrict__ w,
                          const float* __restrict__ b, unsigned short* __restrict__ out) {
  const int row = blockIdx.x;
  const int tid = threadIdx.x;
  const float* xr = x + (size_t)row * DM;
  float4 v0 = ((const float4*)xr)[tid * 2 + 0];
  float4 v1 = ((const float4*)xr)[tid * 2 + 1];
  float ss = v0.x*v0.x + v0.y*v0.y + v0.z*v0.z + v0.w*v0.w
           + v1.x*v1.x + v1.y*v1.y + v1.z*v1.z + v1.w*v1.w;
  #pragma unroll
  for (int o = 1; o < 64; o <<= 1) ss += __shfl_xor(ss, o, 64);
  __shared__ float red[4];
  if ((tid & 63) == 0) red[tid >> 6] = ss;
  __syncthreads();
  float tot = red[0] + red[1] + red[2] + red[3];
  float inv = rsqrtf(tot * (1.0f / DM) + 1e-5f);
  float4 w0 = ((const float4*)w)[tid * 2 + 0];
  float4 w1 = ((const float4*)w)[tid * 2 + 1];
  float4 b0 = ((const float4*)b)[tid * 2 + 0];
  float4 b1 = ((const float4*)b)[tid * 2 + 1];
  u16x8 o8;
  o8[0] = f2bf(v0.x * inv * w0.x + b0.x);
  o8[1] = f2bf(v0.y * inv * w0.y + b0.y);
  o8[2] = f2bf(v0.z * inv * w0.z + b0.z);
  o8[3] = f2bf(v0.w * inv * w0.w + b0.w);
  o8[4] = f2bf(v1.x * inv * w1.x + b1.x);
  o8[5] = f2bf(v1.y * inv * w1.y + b1.y);
  o8[6] = f2bf(v1.z * inv * w1.z + b1.z);
  o8[7] = f2bf(v1.w * inv * w1.w + b1.w);
  *(u16x8*)&out[(size_t)row * DM + tid * 8] = o8;
}

// ---------------- RoPE table + apply ----------------
__global__ void rope_table_k(float2* __restrict__ tab) {
  int idx = blockIdx.x * 256 + threadIdx.x;   // SEQ*64
  int l = idx >> 6, i = idx & 63;
  // freq = 10000^(-i/64) = exp(-ln(10000)*i/64)
  float freq = __expf(-9.210340371976184f * (float)i * (1.0f / 64.0f));
  float ang = (float)l * freq;
  tab[idx] = make_float2(cosf(ang), sinf(ang));
}

__global__ void rope_apply_k(unsigned short* __restrict__ q, unsigned short* __restrict__ k,
                             const float2* __restrict__ tab) {
  int idx = blockIdx.x * 256 + threadIdx.x;  // SEQ*NH*64
  int i = idx & 63;
  int h = (idx >> 6) & (NH - 1);
  int l = idx >> 10;
  float2 cs = tab[(l << 6) | i];
  size_t base = (size_t)l * DM + h * HD + i;
  {
    float a = bf2f(q[base]), b = bf2f(q[base + 64]);
    q[base]      = f2bf(a * cs.x - b * cs.y);
    q[base + 64] = f2bf(b * cs.x + a * cs.y);
  }
  {
    float a = bf2f(k[base]), b = bf2f(k[base + 64]);
    k[base]      = f2bf(a * cs.x - b * cs.y);
    k[base + 64] = f2bf(b * cs.x + a * cs.y);
  }
}

// ---------------- GEMM: C[M,N] = A[M,K] * B[N,K]^T  (bf16 in, epilogues) ---
// EPI 0: out bf16       1: +resid -> f32      2: +bias, relu -> bf16
// EPI 3: +bias +resid -> f32
template<int EPI>
__launch_bounds__(256, 2)
__global__ void gemm_nt(const unsigned short* __restrict__ A,
                        const unsigned short* __restrict__ B,
                        int M, int N, int K,
                        unsigned short* __restrict__ outb,
                        float* __restrict__ outf,
                        const float* __restrict__ bias,
                        const float* __restrict__ resid) {
  __shared__ alignas(16) unsigned short Asm[128 * 32];
  __shared__ alignas(16) unsigned short Bsm[128 * 32];
  const int tid  = threadIdx.x;
  const int lane = tid & 63;
  const int wave = tid >> 6;
  const int wr = wave >> 1, wc = wave & 1;
  const int l16 = lane & 15, lgrp = lane >> 4;
  const int bm = blockIdx.y * 128;
  const int bn = blockIdx.x * 128;

  const f32x4 z = {0.f, 0.f, 0.f, 0.f};
  f32x4 acc[4][4];
  #pragma unroll
  for (int i = 0; i < 4; i++)
    #pragma unroll
    for (int j = 0; j < 4; j++) acc[i][j] = z;

  const int srow = tid >> 2;
  const int scol = (tid & 3) * 8;
  const unsigned short* Ag = A + (size_t)(bm + srow) * K + scol;
  const unsigned short* Bg = B + (size_t)(bn + srow) * K + scol;
  unsigned short* Al = &Asm[(wave * 16) * 32];
  unsigned short* Bl = &Bsm[(wave * 16) * 32];

  const int nk = K >> 5;
  for (int kt = 0; kt < nk; ++kt) {
    const unsigned short* ag = Ag + kt * 32;
    const unsigned short* bg = Bg + kt * 32;
    gload_lds16(ag,                 Al);
    gload_lds16(ag + (size_t)64 * K, Al + 64 * 32);
    gload_lds16(bg,                 Bl);
    gload_lds16(bg + (size_t)64 * K, Bl + 64 * 32);
    __syncthreads();
    bf16x8 af[4], bfr[4];
    #pragma unroll
    for (int i = 0; i < 4; i++) af[i]  = *(const bf16x8*)&Asm[(wr * 64 + i * 16 + l16) * 32 + lgrp * 8];
    #pragma unroll
    for (int j = 0; j < 4; j++) bfr[j] = *(const bf16x8*)&Bsm[(wc * 64 + j * 16 + l16) * 32 + lgrp * 8];
    #pragma unroll
    for (int i = 0; i < 4; i++)
      #pragma unroll
      for (int j = 0; j < 4; j++)
        acc[i][j] = __builtin_amdgcn_mfma_f32_16x16x32_bf16(af[i], bfr[j], acc[i][j], 0, 0, 0);
    __syncthreads();
  }

  #pragma unroll
  for (int i = 0; i < 4; i++)
    #pragma unroll
    for (int j = 0; j < 4; j++)
      #pragma unroll
      for (int r = 0; r < 4; r++) {
        int row = bm + wr * 64 + i * 16 + lgrp * 4 + r;
        int col = bn + wc * 64 + j * 16 + l16;
        size_t off = (size_t)row * N + col;
        float v = acc[i][j][r];
        if constexpr (EPI == 0) {
          outb[off] = f2bf(v);
        } else if constexpr (EPI == 1) {
          outf[off] = v + resid[off];
        } else if constexpr (EPI == 2) {
          v += bias[col];
          outb[off] = f2bf(v > 0.f ? v : 0.f);
        } else {
          outf[off] = v + bias[col] + resid[off];
        }
      }
}

// ---------------- Flash attention (causal), bf16 in/out ----------------
// grid: (SEQ/64, NH), 256 thr. Wave w owns Q rows [q0+16w, q0+16w+16).
__launch_bounds__(256, 2)
__global__ void flash_attn_k(const unsigned short* __restrict__ Q,
                             const unsigned short* __restrict__ K,
                             const unsigned short* __restrict__ V,
                             unsigned short* __restrict__ O) {
  __shared__ alignas(16) unsigned short Ksm[64 * 136];   // [64][128+8]
  __shared__ alignas(16) unsigned short Vsm[128 * 72];   // V^T: [128][64+8]
  __shared__ alignas(16) unsigned short Psm[4][16 * 72]; // per wave [16][64+8]
  const int tid  = threadIdx.x;
  const int lane = tid & 63;
  const int wave = tid >> 6;
  const int l16 = lane & 15, lgrp = lane >> 4;
  const int q0 = blockIdx.x * 64;
  const int h  = blockIdx.y;
  const float scale = 0.08838834764831845f;  // 1/sqrt(128)
  const f32x4 z = {0.f, 0.f, 0.f, 0.f};

  bf16x8 qf[4];
  {
    const unsigned short* qp = Q + (size_t)(q0 + wave * 16 + l16) * DM + h * HD + lgrp * 8;
    #pragma unroll
    for (int kk = 0; kk < 4; kk++) qf[kk] = *(const bf16x8*)(qp + kk * 32);
  }
  f32x4 o[8];
  #pragma unroll
  for (int n = 0; n < 8; n++) o[n] = z;
  float m[4], lsum[4];
  #pragma unroll
  for (int r = 0; r < 4; r++) { m[r] = -3e38f; lsum[r] = 0.f; }

  const int kj = tid >> 2;          // K stage: row 0..63
  const int kc = (tid & 3) * 32;    //          col block
  const int vj = tid & 63;          // V stage: row
  const int vd = (tid >> 6) * 32;   //          d block

  const int ktiles = blockIdx.x + 1;
  for (int jt = 0; jt < ktiles; ++jt) {
    __syncthreads();
    { // stage K tile [64][128] -> padded LDS
      const unsigned short* kp = K + (size_t)(jt * 64 + kj) * DM + h * HD + kc;
      unsigned short* dst = &Ksm[kj * 136 + kc];
      #pragma unroll
      for (int u = 0; u < 4; u++) *(uint4*)(dst + u * 8) = *(const uint4*)(kp + u * 8);
    }
    { // stage V tile transposed -> Vsm[d][j]
      const unsigned short* vp = V + (size_t)(jt * 64 + vj) * DM + h * HD + vd;
      unsigned short tmp[32];
      #pragma unroll
      for (int u = 0; u < 4; u++) *(uint4*)&tmp[u * 8] = *(const uint4*)(vp + u * 8);
      #pragma unroll
      for (int u = 0; u < 32; u++) Vsm[(vd + u) * 72 + vj] = tmp[u];
    }
    __syncthreads();

    // S = scale * Q K^T  (16 rows x 64 cols per wave)
    f32x4 s[4];
    #pragma unroll
    for (int cb = 0; cb < 4; cb++) {
      f32x4 a = z;
      #pragma unroll
      for (int kk = 0; kk < 4; kk++) {
        bf16x8 kf = *(const bf16x8*)&Ksm[(cb * 16 + l16) * 136 + kk * 32 + lgrp * 8];
        a = __builtin_amdgcn_mfma_f32_16x16x32_bf16(qf[kk], kf, a, 0, 0, 0);
      }
      s[cb] = a * scale;
    }
    if (jt == blockIdx.x) {  // causal mask on diagonal tile
      #pragma unroll
      for (int cb = 0; cb < 4; cb++)
        #pragma unroll
        for (int r = 0; r < 4; r++) {
          int jg = jt * 64 + cb * 16 + l16;
          int qg = q0 + wave * 16 + lgrp * 4 + r;
          if (jg > qg) s[cb][r] = -3e38f;
        }
    }
    // online softmax (rows live on 16-lane groups; reduce over lanes 0..15)
    float tm[4];
    #pragma unroll
    for (int r = 0; r < 4; r++) tm[r] = fmaxf(fmaxf(s[0][r], s[1][r]), fmaxf(s[2][r], s[3][r]));
    #pragma unroll
    for (int off = 1; off < 16; off <<= 1)
      #pragma unroll
      for (int r = 0; r < 4; r++) tm[r] = fmaxf(tm[r], __shfl_xor(tm[r], off, 64));
    float alpha[4], ts[4];
    #pragma unroll
    for (int r = 0; r < 4; r++) {
      float nm = fmaxf(m[r], tm[r]);
      alpha[r] = __expf(m[r] - nm);
      m[r] = nm;
      ts[r] = 0.f;
    }
    #pragma unroll
    for (int cb = 0; cb < 4; cb++)
      #pragma unroll
      for (int r = 0; r < 4; r++) {
        float p = __expf(s[cb][r] - m[r]);
        s[cb][r] = p;
        ts[r] += p;
      }
    #pragma unroll
    for (int off = 1; off < 16; off <<= 1)
      #pragma unroll
      for (int r = 0; r < 4; r++) ts[r] += __shfl_xor(ts[r], off, 64);
    #pragma unroll
    for (int r = 0; r < 4; r++) lsum[r] = lsum[r] * alpha[r] + ts[r];
    #pragma unroll
    for (int n = 0; n < 8; n++)
      #pragma unroll
      for (int r = 0; r < 4; r++) o[n][r] *= alpha[r];

    // P (C-layout) -> per-wave LDS -> A-fragments
    unsigned short* pw = &Psm[wave][0];
    #pragma unroll
    for (int cb = 0; cb < 4; cb++)
      #pragma unroll
      for (int r = 0; r < 4; r++)
        pw[(lgrp * 4 + r) * 72 + cb * 16 + l16] = f2bf(s[cb][r]);

    #pragma unroll
    for (int kk2 = 0; kk2 < 2; kk2++) {
      bf16x8 pf = *(const bf16x8*)&pw[l16 * 72 + kk2 * 32 + lgrp * 8];
      #pragma unroll
      for (int n = 0; n < 8; n++) {
        bf16x8 vf = *(const bf16x8*)&Vsm[(n * 16 + l16) * 72 + kk2 * 32 + lgrp * 8];
        o[n] = __builtin_amdgcn_mfma_f32_16x16x32_bf16(pf, vf, o[n], 0, 0, 0);
      }
    }
  }

  #pragma unroll
  for (int n = 0; n < 8; n++)
    #pragma unroll
    for (int r = 0; r < 4; r++) {
      int row = q0 + wave * 16 + lgrp * 4 + r;
      float val = o[n][r] / lsum[r];
      O[(size_t)row * DM + h * HD + n * 16 + l16] = f2bf(val);
    }
}

// ---------------- host ----------------
extern "C" void kernel_launch(void* const* d_in, const int* in_sizes, int n_in,
                              void* d_out, int out_size, void* d_ws, size_t ws_size,
                              hipStream_t stream) {
  const float* x  = (const float*)d_in[0];
  const float* Wq = (const float*)d_in[1];
  const float* Wk = (const float*)d_in[2];
  const float* Wv = (const float*)d_in[3];
  const float* Wo = (const float*)d_in[4];
  const float* rw = (const float*)d_in[5];
  const float* rb = (const float*)d_in[6];
  const float* W1 = (const float*)d_in[7];
  const float* b1 = (const float*)d_in[8];
  const float* W2 = (const float*)d_in[9];
  const float* b2 = (const float*)d_in[10];
  const float* W3 = (const float*)d_in[11];
  const float* b3 = (const float*)d_in[12];
  float* out = (float*)d_out;

  char* p = (char*)d_ws;
  auto carve = [&](size_t bytes) { char* r = p; p += (bytes + 255) & ~(size_t)255; return r; };
  unsigned short* wqb = (unsigned short*)carve((size_t)DM * DM * 2);
  unsigned short* wkb = (unsigned short*)carve((size_t)DM * DM * 2);
  unsigned short* wvb = (unsigned short*)carve((size_t)DM * DM * 2);
  unsigned short* wob = (unsigned short*)carve((size_t)DM * DM * 2);
  unsigned short* w1b = (unsigned short*)carve((size_t)DFF * DM * 2);
  unsigned short* w2b = (unsigned short*)carve((size_t)DFF * DFF * 2);
  unsigned short* w3b = (unsigned short*)carve((size_t)DM * DFF * 2);
  unsigned short* xn  = (unsigned short*)carve((size_t)SEQ * DM * 2);
  unsigned short* qb  = (unsigned short*)carve((size_t)SEQ * DM * 2);
  unsigned short* kb  = (unsigned short*)carve((size_t)SEQ * DM * 2);
  unsigned short* vb  = (unsigned short*)carve((size_t)SEQ * DM * 2);
  unsigned short* h1  = (unsigned short*)carve((size_t)SEQ * DFF * 2);
  unsigned short* h2  = (unsigned short*)carve((size_t)SEQ * DFF * 2);
  float2* tab         = (float2*)carve((size_t)SEQ * 64 * sizeof(float2));
  // reuse: attention output overwrites xn (dead after V-proj); x1n overwrites q
  unsigned short* attnb = xn;
  unsigned short* x1n   = qb;
  float* x1 = out;  // residual-1 result lives in d_out (re-read by final epilogue)

  auto cast = [&](const float* src, unsigned short* dst, size_t n) {
    int n4 = (int)(n / 4);
    cast_f32_bf16<<<(n4 + 255) / 256, 256, 0, stream>>>((const float4*)src, dst, n4);
  };
  cast(Wq, wqb, (size_t)DM * DM);
  cast(Wk, wkb, (size_t)DM * DM);
  cast(Wv, wvb, (size_t)DM * DM);
  cast(Wo, wob, (size_t)DM * DM);
  cast(W1, w1b, (size_t)DFF * DM);
  cast(W2, w2b, (size_t)DFF * DFF);
  cast(W3, w3b, (size_t)DM * DFF);

  rope_table_k<<<(SEQ * 64) / 256, 256, 0, stream>>>(tab);
  rmsnorm_k<<<SEQ, 256, 0, stream>>>(x, rw, rb, xn);

  gemm_nt<0><<<dim3(DM / 128, SEQ / 128), 256, 0, stream>>>(xn, wqb, SEQ, DM, DM, qb, nullptr, nullptr, nullptr);
  gemm_nt<0><<<dim3(DM / 128, SEQ / 128), 256, 0, stream>>>(xn, wkb, SEQ, DM, DM, kb, nullptr, nullptr, nullptr);
  gemm_nt<0><<<dim3(DM / 128, SEQ / 128), 256, 0, stream>>>(xn, wvb, SEQ, DM, DM, vb, nullptr, nullptr, nullptr);

  rope_apply_k<<<(SEQ * NH * 64) / 256, 256, 0, stream>>>(qb, kb, tab);

  flash_attn_k<<<dim3(SEQ / 64, NH), 256, 0, stream>>>(qb, kb, vb, attnb);

  // x1 = x + attn @ Wo^T   (f32, into d_out)
  gemm_nt<1><<<dim3(DM / 128, SEQ / 128), 256, 0, stream>>>(attnb, wob, SEQ, DM, DM, nullptr, x1, nullptr, x);

  rmsnorm_k<<<SEQ, 256, 0, stream>>>(x1, rw, rb, x1n);

  // h1 = relu(x1n @ W1^T + b1)
  gemm_nt<2><<<dim3(DFF / 128, SEQ / 128), 256, 0, stream>>>(x1n, w1b, SEQ, DFF, DM, h1, nullptr, b1, nullptr);
  // h2 = relu(h1 @ W2^T + b2)
  gemm_nt<2><<<dim3(DFF / 128, SEQ / 128), 256, 0, stream>>>(h1, w2b, SEQ, DFF, DFF, h2, nullptr, b2, nullptr);
  // out = x1 + h2 @ W3^T + b3
  gemm_nt<3><<<dim3(DM / 128, SEQ / 128), 256, 0, stream>>>(h2, w3b, SEQ, DM, DFF, nullptr, out, b3, x1);
}